// Round 13
// baseline (331.535 us; speedup 1.0000x reference)
//
#include <hip/hip_runtime.h>
#include <hip/hip_fp16.h>

#define D 64
#define BSHIFT 10              // nodes per bucket = 1024
#define BMASK ((1 << BSHIFT) - 1)
#define NBUK_MAX 256
#define T_TILE 6144            // edges per k_bin block (256 threads x 24)
#define CAP 20480              // per-bucket srcs/ebuf capacity (mean 16327, sigma~127)

#if defined(__has_builtin)
#if __has_builtin(__builtin_amdgcn_fdot2)
#define HAVE_FDOT2 1
#endif
#endif

typedef _Float16 h2f __attribute__((ext_vector_type(2)));
typedef _Float16 half8v __attribute__((ext_vector_type(8)));
typedef float f4v __attribute__((ext_vector_type(4)));

// inclusive wave scan (64 lanes)
__device__ __forceinline__ int wave_iscan(int v, int lane) {
#pragma unroll
    for (int off = 1; off < 64; off <<= 1) {
        int u = __shfl_up(v, off, 64);
        if (lane >= off) v += u;
    }
    return v;
}

// block-wide (256 thr) exclusive scan; returns exclusive prefix
__device__ __forceinline__ int block_escan(int v, int tid, int* wtot /*>=4 ints LDS*/) {
    int lane = tid & 63, w = tid >> 6;
    int inc = wave_iscan(v, lane);
    if (lane == 63) wtot[w] = inc;
    __syncthreads();
    int addv = 0;
#pragma unroll
    for (int q = 0; q < 4; q++) addv += (q < w) ? wtot[q] : 0;
    return inc - v + addv;
}

__device__ __forceinline__ float4 h4_to_f4(uint2 u) {
    __half2 a = *(__half2*)&u.x, b = *(__half2*)&u.y;
    float2 fa = __half22float2(a), fb = __half22float2(b);
    return make_float4(fa.x, fa.y, fb.x, fb.y);
}

// acc[0..3] += fp16x4(u) — 4 v_dot2_f32_f16 when available
__device__ __forceinline__ void acc_u2(float* acc, uint2 u) {
#ifdef HAVE_FDOT2
    h2f a0, a1;
    __builtin_memcpy(&a0, &u.x, 4);
    __builtin_memcpy(&a1, &u.y, 4);
    const h2f LO = {(_Float16)1.0f, (_Float16)0.0f};
    const h2f HI = {(_Float16)0.0f, (_Float16)1.0f};
    acc[0] = __builtin_amdgcn_fdot2(a0, LO, acc[0], false);
    acc[1] = __builtin_amdgcn_fdot2(a0, HI, acc[1], false);
    acc[2] = __builtin_amdgcn_fdot2(a1, LO, acc[2], false);
    acc[3] = __builtin_amdgcn_fdot2(a1, HI, acc[3], false);
#else
    float4 v = h4_to_f4(u);
    acc[0] += v.x; acc[1] += v.y; acc[2] += v.z; acc[3] += v.w;
#endif
}

// ---------------- bucket binning with LDS stage+reorder (coalesced run writes) -------------
// packed entry: (c & BMASK) << 18 | r   — requires N <= 2^18 (N=200000 here)
// bucket b region of ebuf: [b*CAP, b*CAP + cnt_b); bbase[b] (memset 0) ends as cnt_b.
// NOTE (R12 lesson): the LDS stage+reorder is essential — it makes CONSECUTIVE LANES write
// consecutive addresses (true coalescing). Direct per-lane cursor scatter regressed 28 µs.

__global__ __launch_bounds__(256) void k_bin(const int* __restrict__ row, const int* __restrict__ col,
                                             int E, int* __restrict__ bbase,
                                             unsigned* __restrict__ ebuf, int nbuk) {
    __shared__ int hist4[4][NBUK_MAX];     // 4 KB
    __shared__ int sexcl[NBUK_MAX];
    __shared__ int cur4[4][NBUK_MAX];      // 4 KB
    __shared__ int gbase[NBUK_MAX];
    __shared__ int wtot[4];
    __shared__ unsigned stage[T_TILE];     // 24 KB
    __shared__ unsigned char sbuk[T_TILE]; // 6 KB
    int tid = threadIdx.x;
    int w = tid >> 6;
    int tile0 = blockIdx.x * T_TILE;
    int cnt = min(T_TILE, E - tile0);

#pragma unroll
    for (int q = 0; q < 4; q++) hist4[q][tid] = 0;
    __syncthreads();
    for (int i = tid; i < cnt; i += 256)
        atomicAdd(&hist4[w][col[tile0 + i] >> BSHIFT], 1);
    __syncthreads();

    int h0 = hist4[0][tid], h1 = hist4[1][tid], h2 = hist4[2][tid], h3 = hist4[3][tid];
    int v = h0 + h1 + h2 + h3;
    int excl = block_escan(v, tid, wtot);
    sexcl[tid] = excl;
    cur4[0][tid] = excl;
    cur4[1][tid] = excl + h0;
    cur4[2][tid] = excl + h0 + h1;
    cur4[3][tid] = excl + h0 + h1 + h2;
    gbase[tid] = (v > 0 && tid < nbuk) ? (tid * CAP + atomicAdd(&bbase[tid], v)) : 0;
    __syncthreads();

    for (int i = tid; i < cnt; i += 256) {
        int r = row[tile0 + i];
        int c = col[tile0 + i];
        int b = c >> BSHIFT;
        int p = atomicAdd(&cur4[w][b], 1);
        stage[p] = ((unsigned)(c & BMASK) << 18) | (unsigned)r;
        sbuk[p] = (unsigned char)b;
    }
    __syncthreads();

    for (int i = tid; i < cnt; i += 256) {
        int b = sbuk[i];
        int gpos = gbase[b] + (i - sexcl[b]);
        ebuf[gpos] = stage[i];
    }
}

// ---------------- csr2a: per-bucket degree count + rps(start,end) + dinv + sentinels -------

__global__ __launch_bounds__(256) void k_csr2a(const unsigned* __restrict__ ebuf,
                                               const int* __restrict__ bbase, int N,
                                               int2* __restrict__ rps, float* __restrict__ dinv,
                                               __half* __restrict__ h, __half* __restrict__ hs2) {
    __shared__ int lcnt[1 << BSHIFT];  // 4 KB
    __shared__ int wtot[4];
    int tid = threadIdx.x;
    int c0 = blockIdx.x << BSHIFT;
    int nn = min(1 << BSHIFT, N - c0);
    int e0 = blockIdx.x * CAP, e1 = e0 + bbase[blockIdx.x];

    if (blockIdx.x == 0 && tid < 32) {  // zero sentinel rows (beyond ebuf alias region)
        uint2 z; z.x = 0u; z.y = 0u;
        if (tid < 16) *(uint2*)(h + (size_t)N * D + tid * 4) = z;
        else *(uint2*)(hs2 + (size_t)N * D + (tid - 16) * 4) = z;
    }

    for (int i = tid; i < (1 << BSHIFT); i += 256) lcnt[i] = 0;
    __syncthreads();
    for (int j = e0 + tid; j < e1; j += 256)
        atomicAdd(&lcnt[ebuf[j] >> 18], 1);
    __syncthreads();

    int c[4]; int s = 0;
#pragma unroll
    for (int i = 0; i < 4; i++) { c[i] = lcnt[tid * 4 + i]; s += c[i]; }
    int run = block_escan(s, tid, wtot);
#pragma unroll
    for (int i = 0; i < 4; i++) {
        int idx = tid * 4 + i;
        if (idx < nn) {
            int st = e0 + run;
            rps[c0 + idx] = make_int2(st, st + c[i]);
            dinv[c0 + idx] = rsqrtf((float)(c[i] + 1));  // +1 self loop
        }
        run += c[i];
    }
}

// ---------------- MFMA gemm compute: out[n][c] = fp16( dinv[n] * sum_k A[n][k] * W[k][c] ) --
// A = Xh[m][k] row-major fp16 LDS (stride 72); Wt[c][k] (= W^T) fp16 LDS (stride 72).
// mfma_f32_16x16x32_f16; C/D col=lane&15, row=quad*4+reg. One wave = 16 nodes x 64 cols.
// NOTE: wave wv only reads Xh rows [wv*16, wv*16+16) — wave-private.

// stage W^T: k = lane (lane-consecutive -> 2-way LDS bank aliasing = free, m136),
// c = i*4 + wave (wave-uniform). Global read W[k*64+c] is lane-strided but W (16 KB) is
// L1-resident. Old c-fast mapping was an 8-way conflict (1.7M SQ_LDS_BANK_CONFLICT, R11).
__device__ __forceinline__ void stage_W(const float* __restrict__ W, __half* __restrict__ Wt, int tid) {
    int lane = tid & 63, w = tid >> 6;
#pragma unroll
    for (int i = 0; i < 16; i++) {
        int c = i * 4 + w;
        Wt[c * 72 + lane] = __float2half(W[lane * 64 + c]);
    }
}

__device__ __forceinline__ void gemm_compute(const __half* __restrict__ Xh, const __half* __restrict__ Wt,
                                             int n0, int N, const float* __restrict__ dinv,
                                             __half* __restrict__ out, int tid) {
    int lane = tid & 63;
    int wv = tid >> 6;
    int n16 = lane & 15, quad = lane >> 4;
    const __half* Xw = Xh + (wv * 16) * 72;
    half8v a0 = *(const half8v*)(Xw + n16 * 72 + quad * 8);
    half8v a1 = *(const half8v*)(Xw + n16 * 72 + quad * 8 + 32);
    f4v acc[4];
#pragma unroll
    for (int ct = 0; ct < 4; ct++) {
        acc[ct] = (f4v){0.f, 0.f, 0.f, 0.f};
        const __half* wp = Wt + (ct * 16 + n16) * 72;
        half8v b0 = *(const half8v*)(wp + quad * 8);
        half8v b1 = *(const half8v*)(wp + quad * 8 + 32);
        acc[ct] = __builtin_amdgcn_mfma_f32_16x16x32_f16(a0, b0, acc[ct], 0, 0, 0);
        acc[ct] = __builtin_amdgcn_mfma_f32_16x16x32_f16(a1, b1, acc[ct], 0, 0, 0);
    }
#pragma unroll
    for (int r = 0; r < 4; r++) {
        int node = n0 + wv * 16 + quad * 4 + r;
        if (node < N) {
            float dv = dinv[node];
#pragma unroll
            for (int ct = 0; ct < 4; ct++)
                out[(size_t)node * D + ct * 16 + n16] = __float2half(acc[ct][r] * dv);
        }
    }
}

// ---------------- fused: csr2b scatter (blocks [0,nbuk)) + gemm layer-1 (rest) ----------------

__global__ __launch_bounds__(256) void k_csr2b_gemm1(const unsigned* __restrict__ ebuf,
                                                     const int2* __restrict__ rps,
                                                     const int* __restrict__ bbase,
                                                     int N, int nbuk, int* __restrict__ srcs,
                                                     const float* __restrict__ xu, const float* __restrict__ xj,
                                                     int U, const float* __restrict__ W,
                                                     const float* __restrict__ dinv, __half* __restrict__ h) {
    __shared__ __align__(16) __half Xh[64 * 72];   // [node][k] (reused as lcur via alias below)
    __shared__ __align__(16) __half Wt[64 * 72];   // [c][k]
    int tid = threadIdx.x;
    if ((int)blockIdx.x < nbuk) {
        int* lcur = (int*)Xh;  // 4 KB of the 9.2 KB tile
        int c0 = blockIdx.x << BSHIFT;
        int e0 = blockIdx.x * CAP, e1 = e0 + bbase[blockIdx.x];
        for (int i = tid; i < (1 << BSHIFT); i += 256)
            lcur[i] = (c0 + i < N) ? rps[c0 + i].x : 0;
        __syncthreads();
        for (int j = e0 + tid; j < e1; j += 256) {
            unsigned pk = ebuf[j];
            int p = atomicAdd(&lcur[pk >> 18], 1);
            srcs[p] = (int)(pk & 0x3ffffu);
        }
    } else {
        int n0 = ((int)blockIdx.x - nbuk) * 64;
        stage_W(W, Wt, tid);
#pragma unroll
        for (int i = 0; i < 4; i++) {
            int e4 = i * 256 + tid;           // 64 nodes x 16 uint2-slots
            int nl = e4 >> 4, k4 = e4 & 15;
            int nn = n0 + nl;
            uint2 st; st.x = 0u; st.y = 0u;
            if (nn < N) {
                const float* src = (nn < U) ? (xu + (size_t)nn * D) : (xj + (size_t)(nn - U) * D);
                float4 v = *(const float4*)(src + k4 * 4);
                __half2 p0 = __floats2half2_rn(v.x, v.y);
                __half2 p1 = __floats2half2_rn(v.z, v.w);
                st.x = *(unsigned*)&p0; st.y = *(unsigned*)&p1;
            }
            *(uint2*)(Xh + nl * 72 + k4 * 4) = st;
        }
        __syncthreads();
        gemm_compute(Xh, Wt, n0, N, dinv, h, tid);
    }
}

// ---------------- gather: 16 lanes per node, 4 nodes per wave-round ----------------
// lane = g*16+t; group g owns one node; lane t owns features [4t,4t+4) (uint2 = 8 B).
// 16 edge indices preloaded per group (sentinel N at load); 4x4 unrolled shfl-broadcast
// + gathers -> 4 loads in flight; NO cross-lane reduction needed.

__device__ __forceinline__ void gather16(float* acc, const __half* __restrict__ hs,
                                         const int2* __restrict__ rps,
                                         const int* __restrict__ srcs,
                                         int node, int N, int g, int t) {
    const __half* hp = hs + t * 4;
    int2 r = rps[node];
    int e0 = r.x, deg = r.y - r.x;
    for (int cb = 0; cb < deg; cb += 16) {
        int sv = (cb + t < deg) ? srcs[e0 + cb + t] : N;
#pragma unroll
        for (int c = 0; c < 4; c++) {
            int base = g * 16 + c * 4;
            int s0 = __shfl(sv, base + 0, 64);
            int s1 = __shfl(sv, base + 1, 64);
            int s2 = __shfl(sv, base + 2, 64);
            int s3 = __shfl(sv, base + 3, 64);
            uint2 u0 = *(const uint2*)(hp + (size_t)s0 * D);
            uint2 u1 = *(const uint2*)(hp + (size_t)s1 * D);
            uint2 u2 = *(const uint2*)(hp + (size_t)s2 * D);
            uint2 u3 = *(const uint2*)(hp + (size_t)s3 * D);
            acc_u2(acc, u0);
            acc_u2(acc, u1);
            acc_u2(acc, u2);
            acc_u2(acc, u3);
        }
    }
}

// ---------------- fused: layer-1 aggregation (64 nodes/block -> LDS) + layer-2 gemm --------
// Wave w aggregates nodes n0+w*16..+15 straight into its own MFMA A-tile rows
// (Xh[nl*72 + t*4], fp16), then runs MFMA with W2 -> hs2. No block barrier after agg:
// A-fragment rows are wave-private; only stage_W needs one barrier up front.

__global__ __launch_bounds__(256) void k_agg_gemm2(const __half* __restrict__ hs, const float* __restrict__ dinv,
                                                   const int2* __restrict__ rps, const int* __restrict__ srcs,
                                                   const float* __restrict__ bias, const float* __restrict__ W2,
                                                   int N, __half* __restrict__ hs2) {
    __shared__ __align__(16) __half Xh[64 * 72];
    __shared__ __align__(16) __half Wt[64 * 72];
    int tid = threadIdx.x;
    int lane = tid & 63;
    int w = tid >> 6;
    int g = lane >> 4, t = lane & 15;
    int n0 = blockIdx.x * 64;

    stage_W(W2, Wt, tid);
    __syncthreads();

    float4 b4 = *(const float4*)(bias + t * 4);
#pragma unroll
    for (int rr = 0; rr < 4; rr++) {
        int nl = w * 16 + rr * 4 + g;
        int node = n0 + nl;
        uint2 st; st.x = 0u; st.y = 0u;
        if (node < N) {
            float acc[4] = {0.f, 0.f, 0.f, 0.f};
            gather16(acc, hs, rps, srcs, node, N, g, t);
            float4 sf = h4_to_f4(*(const uint2*)(hs + (size_t)node * D + t * 4));
            float dv = dinv[node];
            float o0 = fmaxf((acc[0] + sf.x) * dv + b4.x, 0.f);
            float o1 = fmaxf((acc[1] + sf.y) * dv + b4.y, 0.f);
            float o2 = fmaxf((acc[2] + sf.z) * dv + b4.z, 0.f);
            float o3 = fmaxf((acc[3] + sf.w) * dv + b4.w, 0.f);
            __half2 p0 = __floats2half2_rn(o0, o1);
            __half2 p1 = __floats2half2_rn(o2, o3);
            st.x = *(unsigned*)&p0; st.y = *(unsigned*)&p1;
        }
        *(uint2*)(Xh + nl * 72 + t * 4) = st;
    }
    // no __syncthreads(): wave reads only its own Xh rows (lgkmcnt ordering within wave)
    gemm_compute(Xh, Wt, n0, N, dinv, hs2, tid);
}

// ---------------- fused layer-2 aggregation + prediction (2 pairs/wave, no atomics) --------

__global__ __launch_bounds__(256) void k_pred(const __half* __restrict__ hs2, const float* __restrict__ dinv,
                                              const int2* __restrict__ rps, const int* __restrict__ srcs,
                                              const float* __restrict__ b2, const float* __restrict__ pw,
                                              const float* __restrict__ pb,
                                              const int* __restrict__ uidx, const int* __restrict__ jidx,
                                              int U, int N, int B, float* __restrict__ out) {
    int tid = threadIdx.x;
    int lane = tid & 63;
    int g = lane >> 4, t = lane & 15;
    int pair = blockIdx.x * 8 + (tid >> 6) * 2 + (g >> 1);
    if (pair >= B) return;
    int side = g & 1;
    int c = side ? (U + jidx[pair]) : uidx[pair];
    float acc[4] = {0.f, 0.f, 0.f, 0.f};
    gather16(acc, hs2, rps, srcs, c, N, g, t);
    float4 sf = h4_to_f4(*(const uint2*)(hs2 + (size_t)c * D + t * 4));
    float4 b4 = *(const float4*)(b2 + t * 4);
    float dv = dinv[c];
    float4 w4 = *(const float4*)(pw + side * 64 + t * 4);
    float vx = ((acc[0] + sf.x) * dv + b4.x) * w4.x
             + ((acc[1] + sf.y) * dv + b4.y) * w4.y
             + ((acc[2] + sf.z) * dv + b4.z) * w4.z
             + ((acc[3] + sf.w) * dv + b4.w) * w4.w;
    vx += __shfl_xor(vx, 1, 64); vx += __shfl_xor(vx, 2, 64);
    vx += __shfl_xor(vx, 4, 64); vx += __shfl_xor(vx, 8, 64);
    vx += __shfl_xor(vx, 16, 64);   // combine user+job groups of this pair
    if ((lane & 31) == 0) out[pair] = vx + pb[0];
}

// ---------------- host ----------------

extern "C" void kernel_launch(void* const* d_in, const int* in_sizes, int n_in,
                              void* d_out, int out_size, void* d_ws, size_t ws_size,
                              hipStream_t stream) {
    const int*   edge = (const int*)d_in[0];
    const int*   uidx = (const int*)d_in[1];
    const int*   jidx = (const int*)d_in[2];
    const float* xu   = (const float*)d_in[3];
    const float* xj   = (const float*)d_in[4];
    const float* W1   = (const float*)d_in[5];
    const float* b1   = (const float*)d_in[6];
    const float* W2   = (const float*)d_in[7];
    const float* b2   = (const float*)d_in[8];
    const float* pw   = (const float*)d_in[9];
    const float* pb   = (const float*)d_in[10];
    float* out = (float*)d_out;

    int E = in_sizes[0] / 2;
    int B = in_sizes[1];
    int U = in_sizes[3] / D;
    int J = in_sizes[4] / D;
    int N = U + J;
    int nbuk = (N + (1 << BSHIFT) - 1) >> BSHIFT;   // 196 for N=200000; must be <= 256
    const int* row = edge;       // sources
    const int* col = edge + E;   // targets

    char* p = (char*)d_ws;
    auto alloc = [&](size_t bytes) -> void* {
        void* q = (void*)p;
        p += (bytes + 255) / 256 * 256;
        return q;
    };
    size_t capsz = (size_t)nbuk * CAP * 4;               // 16.06 MB
    size_t hs2sz = (size_t)(N + 1) * D * 2;              // 25.6 MB (+ sentinel row)
    int*    bbase   = (int*)alloc(256 * 4);
    int2*   rps     = (int2*)alloc((size_t)N * 8);
    float*  dinv    = (float*)alloc((size_t)N * 4);
    int*    srcs    = (int*)alloc(capsz);
    __half* h       = (__half*)alloc((size_t)(N + 1) * D * 2);  // layer-1 hs (+ sentinel)
    __half* hs2     = (__half*)alloc(hs2sz > capsz ? hs2sz : capsz);
    unsigned* ebuf  = (unsigned*)hs2;                     // ebuf aliases hs2 (dead until agg_gemm2)

    hipMemsetAsync(bbase, 0, 256 * 4, stream);

    // CSR build: staged bucketed binning into fixed-CAP regions, then per-bucket count+scan
    k_bin<<<(E + T_TILE - 1) / T_TILE, 256, 0, stream>>>(row, col, E, bbase, ebuf, nbuk);
    k_csr2a<<<nbuk, 256, 0, stream>>>(ebuf, bbase, N, rps, dinv, h, hs2);

    // fused: srcs scatter (196 blocks) + layer-1 gemm (3125 blocks) — independent work overlapped
    k_csr2b_gemm1<<<nbuk + (N + 63) / 64, 256, 0, stream>>>(ebuf, rps, bbase, N, nbuk, srcs,
                                                            xu, xj, U, W1, dinv, h);

    // fused: layer-1 aggregation (relu, -> wave-private LDS A-rows) + layer-2 gemm -> hs2
    k_agg_gemm2<<<(N + 63) / 64, 256, 0, stream>>>(h, dinv, rps, srcs, b1, W2, N, hs2);

    // layer-2 selected-node aggregation fused with predictor
    k_pred<<<(B + 7) / 8, 256, 0, stream>>>(hs2, dinv, rps, srcs, b2, pw, pb, uidx, jidx, U, N, B, out);
}

// Round 14
// 296.396 us; speedup vs baseline: 1.1186x; 1.1186x over previous
//
#include <hip/hip_runtime.h>
#include <hip/hip_fp16.h>

#define D 64
#define BSHIFT 10              // nodes per bucket = 1024
#define BMASK ((1 << BSHIFT) - 1)
#define NBUK_MAX 256
#define T_TILE 6144            // edges per k_bin block (256 threads x 24)
#define CAP 20480              // per-bucket srcs/ebuf capacity (mean 16327, sigma~127)

#if defined(__has_builtin)
#if __has_builtin(__builtin_amdgcn_fdot2)
#define HAVE_FDOT2 1
#endif
#endif

typedef _Float16 h2f __attribute__((ext_vector_type(2)));
typedef _Float16 half8v __attribute__((ext_vector_type(8)));
typedef float f4v __attribute__((ext_vector_type(4)));

// inclusive wave scan (64 lanes)
__device__ __forceinline__ int wave_iscan(int v, int lane) {
#pragma unroll
    for (int off = 1; off < 64; off <<= 1) {
        int u = __shfl_up(v, off, 64);
        if (lane >= off) v += u;
    }
    return v;
}

// block-wide (256 thr) exclusive scan; returns exclusive prefix
__device__ __forceinline__ int block_escan(int v, int tid, int* wtot /*>=4 ints LDS*/) {
    int lane = tid & 63, w = tid >> 6;
    int inc = wave_iscan(v, lane);
    if (lane == 63) wtot[w] = inc;
    __syncthreads();
    int addv = 0;
#pragma unroll
    for (int q = 0; q < 4; q++) addv += (q < w) ? wtot[q] : 0;
    return inc - v + addv;
}

__device__ __forceinline__ float4 h4_to_f4(uint2 u) {
    __half2 a = *(__half2*)&u.x, b = *(__half2*)&u.y;
    float2 fa = __half22float2(a), fb = __half22float2(b);
    return make_float4(fa.x, fa.y, fb.x, fb.y);
}

// acc[0..3] += fp16x4(u) — 4 v_dot2_f32_f16 when available
__device__ __forceinline__ void acc_u2(float* acc, uint2 u) {
#ifdef HAVE_FDOT2
    h2f a0, a1;
    __builtin_memcpy(&a0, &u.x, 4);
    __builtin_memcpy(&a1, &u.y, 4);
    const h2f LO = {(_Float16)1.0f, (_Float16)0.0f};
    const h2f HI = {(_Float16)0.0f, (_Float16)1.0f};
    acc[0] = __builtin_amdgcn_fdot2(a0, LO, acc[0], false);
    acc[1] = __builtin_amdgcn_fdot2(a0, HI, acc[1], false);
    acc[2] = __builtin_amdgcn_fdot2(a1, LO, acc[2], false);
    acc[3] = __builtin_amdgcn_fdot2(a1, HI, acc[3], false);
#else
    float4 v = h4_to_f4(u);
    acc[0] += v.x; acc[1] += v.y; acc[2] += v.z; acc[3] += v.w;
#endif
}

// ---------------- bucket binning with LDS stage+reorder (coalesced run writes) -------------
// packed entry: (c & BMASK) << 18 | r   — requires N <= 2^18 (N=200000 here)
// bucket b region of ebuf: [b*CAP, b*CAP + cnt_b); bbase[b] (memset 0) ends as cnt_b.
// NOTE (R12 lesson): the LDS stage+reorder is essential — it makes CONSECUTIVE LANES write
// consecutive addresses (true coalescing). Direct per-lane cursor scatter regressed 28 µs.

__global__ __launch_bounds__(256) void k_bin(const int* __restrict__ row, const int* __restrict__ col,
                                             int E, int* __restrict__ bbase,
                                             unsigned* __restrict__ ebuf, int nbuk) {
    __shared__ int hist4[4][NBUK_MAX];     // 4 KB
    __shared__ int sexcl[NBUK_MAX];
    __shared__ int cur4[4][NBUK_MAX];      // 4 KB
    __shared__ int gbase[NBUK_MAX];
    __shared__ int wtot[4];
    __shared__ unsigned stage[T_TILE];     // 24 KB
    __shared__ unsigned char sbuk[T_TILE]; // 6 KB
    int tid = threadIdx.x;
    int w = tid >> 6;
    int tile0 = blockIdx.x * T_TILE;
    int cnt = min(T_TILE, E - tile0);

#pragma unroll
    for (int q = 0; q < 4; q++) hist4[q][tid] = 0;
    __syncthreads();
    for (int i = tid; i < cnt; i += 256)
        atomicAdd(&hist4[w][col[tile0 + i] >> BSHIFT], 1);
    __syncthreads();

    int h0 = hist4[0][tid], h1 = hist4[1][tid], h2 = hist4[2][tid], h3 = hist4[3][tid];
    int v = h0 + h1 + h2 + h3;
    int excl = block_escan(v, tid, wtot);
    sexcl[tid] = excl;
    cur4[0][tid] = excl;
    cur4[1][tid] = excl + h0;
    cur4[2][tid] = excl + h0 + h1;
    cur4[3][tid] = excl + h0 + h1 + h2;
    gbase[tid] = (v > 0 && tid < nbuk) ? (tid * CAP + atomicAdd(&bbase[tid], v)) : 0;
    __syncthreads();

    for (int i = tid; i < cnt; i += 256) {
        int r = row[tile0 + i];
        int c = col[tile0 + i];
        int b = c >> BSHIFT;
        int p = atomicAdd(&cur4[w][b], 1);
        stage[p] = ((unsigned)(c & BMASK) << 18) | (unsigned)r;
        sbuk[p] = (unsigned char)b;
    }
    __syncthreads();

    for (int i = tid; i < cnt; i += 256) {
        int b = sbuk[i];
        int gpos = gbase[b] + (i - sexcl[b]);
        ebuf[gpos] = stage[i];
    }
}

// ---------------- csr2a: per-bucket degree count + rps(start,end) + dinv + sentinels -------

__global__ __launch_bounds__(256) void k_csr2a(const unsigned* __restrict__ ebuf,
                                               const int* __restrict__ bbase, int N,
                                               int2* __restrict__ rps, float* __restrict__ dinv,
                                               __half* __restrict__ h, __half* __restrict__ hs2) {
    __shared__ int lcnt[1 << BSHIFT];  // 4 KB
    __shared__ int wtot[4];
    int tid = threadIdx.x;
    int c0 = blockIdx.x << BSHIFT;
    int nn = min(1 << BSHIFT, N - c0);
    int e0 = blockIdx.x * CAP, e1 = e0 + bbase[blockIdx.x];

    if (blockIdx.x == 0 && tid < 32) {  // zero sentinel rows (beyond ebuf alias region)
        uint2 z; z.x = 0u; z.y = 0u;
        if (tid < 16) *(uint2*)(h + (size_t)N * D + tid * 4) = z;
        else *(uint2*)(hs2 + (size_t)N * D + (tid - 16) * 4) = z;
    }

    for (int i = tid; i < (1 << BSHIFT); i += 256) lcnt[i] = 0;
    __syncthreads();
    for (int j = e0 + tid; j < e1; j += 256)
        atomicAdd(&lcnt[ebuf[j] >> 18], 1);
    __syncthreads();

    int c[4]; int s = 0;
#pragma unroll
    for (int i = 0; i < 4; i++) { c[i] = lcnt[tid * 4 + i]; s += c[i]; }
    int run = block_escan(s, tid, wtot);
#pragma unroll
    for (int i = 0; i < 4; i++) {
        int idx = tid * 4 + i;
        if (idx < nn) {
            int st = e0 + run;
            rps[c0 + idx] = make_int2(st, st + c[i]);
            dinv[c0 + idx] = rsqrtf((float)(c[i] + 1));  // +1 self loop
        }
        run += c[i];
    }
}

// ---------------- MFMA gemm compute: out[n][c] = fp16( dinv[n] * sum_k A[n][k] * W[k][c] ) --
// A = Xh[m][k] row-major fp16 LDS (stride 72); Wt[c][k] (= W^T) fp16 LDS (stride 72).
// mfma_f32_16x16x32_f16; C/D col=lane&15, row=quad*4+reg. One wave = 16 nodes x 64 cols.
// NOTE: wave wv only reads Xh rows [wv*16, wv*16+16) — wave-private.

// stage W^T, R11 form: global read W[e] with e=i*256+tid is COALESCED (consecutive lanes,
// consecutive floats). LDS write c*72+k has 8-way bank aliasing (~1.7M conflicts, ~1-2 µs)
// — accepted. R13 lesson: flipping the mapping to fix LDS banks made the GLOBAL read
// 64-lines-per-instruction uncoalesced and cost 16 µs. Both sides must stay lane-contiguous.
__device__ __forceinline__ void stage_W(const float* __restrict__ W, __half* __restrict__ Wt, int tid) {
#pragma unroll
    for (int i = 0; i < 16; i++) {
        int e = i * 256 + tid;            // e = k*64 + c
        int k = e >> 6, c = e & 63;
        Wt[c * 72 + k] = __float2half(W[e]);
    }
}

__device__ __forceinline__ void gemm_compute(const __half* __restrict__ Xh, const __half* __restrict__ Wt,
                                             int n0, int N, const float* __restrict__ dinv,
                                             __half* __restrict__ out, int tid) {
    int lane = tid & 63;
    int wv = tid >> 6;
    int n16 = lane & 15, quad = lane >> 4;
    const __half* Xw = Xh + (wv * 16) * 72;
    half8v a0 = *(const half8v*)(Xw + n16 * 72 + quad * 8);
    half8v a1 = *(const half8v*)(Xw + n16 * 72 + quad * 8 + 32);
    f4v acc[4];
#pragma unroll
    for (int ct = 0; ct < 4; ct++) {
        acc[ct] = (f4v){0.f, 0.f, 0.f, 0.f};
        const __half* wp = Wt + (ct * 16 + n16) * 72;
        half8v b0 = *(const half8v*)(wp + quad * 8);
        half8v b1 = *(const half8v*)(wp + quad * 8 + 32);
        acc[ct] = __builtin_amdgcn_mfma_f32_16x16x32_f16(a0, b0, acc[ct], 0, 0, 0);
        acc[ct] = __builtin_amdgcn_mfma_f32_16x16x32_f16(a1, b1, acc[ct], 0, 0, 0);
    }
#pragma unroll
    for (int r = 0; r < 4; r++) {
        int node = n0 + wv * 16 + quad * 4 + r;
        if (node < N) {
            float dv = dinv[node];
#pragma unroll
            for (int ct = 0; ct < 4; ct++)
                out[(size_t)node * D + ct * 16 + n16] = __float2half(acc[ct][r] * dv);
        }
    }
}

// ---------------- fused: csr2b scatter (blocks [0,nbuk)) + gemm layer-1 (rest) ----------------

__global__ __launch_bounds__(256) void k_csr2b_gemm1(const unsigned* __restrict__ ebuf,
                                                     const int2* __restrict__ rps,
                                                     const int* __restrict__ bbase,
                                                     int N, int nbuk, int* __restrict__ srcs,
                                                     const float* __restrict__ xu, const float* __restrict__ xj,
                                                     int U, const float* __restrict__ W,
                                                     const float* __restrict__ dinv, __half* __restrict__ h) {
    __shared__ __align__(16) __half Xh[64 * 72];   // [node][k] (reused as lcur via alias below)
    __shared__ __align__(16) __half Wt[64 * 72];   // [c][k]
    int tid = threadIdx.x;
    if ((int)blockIdx.x < nbuk) {
        int* lcur = (int*)Xh;  // 4 KB of the 9.2 KB tile
        int c0 = blockIdx.x << BSHIFT;
        int e0 = blockIdx.x * CAP, e1 = e0 + bbase[blockIdx.x];
        for (int i = tid; i < (1 << BSHIFT); i += 256)
            lcur[i] = (c0 + i < N) ? rps[c0 + i].x : 0;
        __syncthreads();
        for (int j = e0 + tid; j < e1; j += 256) {
            unsigned pk = ebuf[j];
            int p = atomicAdd(&lcur[pk >> 18], 1);
            srcs[p] = (int)(pk & 0x3ffffu);
        }
    } else {
        int n0 = ((int)blockIdx.x - nbuk) * 64;
        stage_W(W, Wt, tid);
#pragma unroll
        for (int i = 0; i < 4; i++) {
            int e4 = i * 256 + tid;           // 64 nodes x 16 uint2-slots
            int nl = e4 >> 4, k4 = e4 & 15;
            int nn = n0 + nl;
            uint2 st; st.x = 0u; st.y = 0u;
            if (nn < N) {
                const float* src = (nn < U) ? (xu + (size_t)nn * D) : (xj + (size_t)(nn - U) * D);
                float4 v = *(const float4*)(src + k4 * 4);
                __half2 p0 = __floats2half2_rn(v.x, v.y);
                __half2 p1 = __floats2half2_rn(v.z, v.w);
                st.x = *(unsigned*)&p0; st.y = *(unsigned*)&p1;
            }
            *(uint2*)(Xh + nl * 72 + k4 * 4) = st;
        }
        __syncthreads();
        gemm_compute(Xh, Wt, n0, N, dinv, h, tid);
    }
}

// ---------------- gather: 16 lanes per node, 4 nodes per wave-round ----------------
// lane = g*16+t; group g owns one node; lane t owns features [4t,4t+4) (uint2 = 8 B).
// 16 edge indices preloaded per group (sentinel N at load); 4x4 unrolled shfl-broadcast
// + gathers -> 4 loads in flight; NO cross-lane reduction needed.

__device__ __forceinline__ void gather16(float* acc, const __half* __restrict__ hs,
                                         const int2* __restrict__ rps,
                                         const int* __restrict__ srcs,
                                         int node, int N, int g, int t) {
    const __half* hp = hs + t * 4;
    int2 r = rps[node];
    int e0 = r.x, deg = r.y - r.x;
    for (int cb = 0; cb < deg; cb += 16) {
        int sv = (cb + t < deg) ? srcs[e0 + cb + t] : N;
#pragma unroll
        for (int c = 0; c < 4; c++) {
            int base = g * 16 + c * 4;
            int s0 = __shfl(sv, base + 0, 64);
            int s1 = __shfl(sv, base + 1, 64);
            int s2 = __shfl(sv, base + 2, 64);
            int s3 = __shfl(sv, base + 3, 64);
            uint2 u0 = *(const uint2*)(hp + (size_t)s0 * D);
            uint2 u1 = *(const uint2*)(hp + (size_t)s1 * D);
            uint2 u2 = *(const uint2*)(hp + (size_t)s2 * D);
            uint2 u3 = *(const uint2*)(hp + (size_t)s3 * D);
            acc_u2(acc, u0);
            acc_u2(acc, u1);
            acc_u2(acc, u2);
            acc_u2(acc, u3);
        }
    }
}

// ---------------- fused: layer-1 aggregation (64 nodes/block -> LDS) + layer-2 gemm --------
// Wave w aggregates nodes n0+w*16..+15 straight into its own MFMA A-tile rows
// (Xh[nl*72 + t*4], fp16), then runs MFMA with W2 -> hs2. No block barrier after agg:
// A-fragment rows are wave-private; only stage_W needs one barrier up front.

__global__ __launch_bounds__(256) void k_agg_gemm2(const __half* __restrict__ hs, const float* __restrict__ dinv,
                                                   const int2* __restrict__ rps, const int* __restrict__ srcs,
                                                   const float* __restrict__ bias, const float* __restrict__ W2,
                                                   int N, __half* __restrict__ hs2) {
    __shared__ __align__(16) __half Xh[64 * 72];
    __shared__ __align__(16) __half Wt[64 * 72];
    int tid = threadIdx.x;
    int lane = tid & 63;
    int w = tid >> 6;
    int g = lane >> 4, t = lane & 15;
    int n0 = blockIdx.x * 64;

    stage_W(W2, Wt, tid);
    __syncthreads();

    float4 b4 = *(const float4*)(bias + t * 4);
#pragma unroll
    for (int rr = 0; rr < 4; rr++) {
        int nl = w * 16 + rr * 4 + g;
        int node = n0 + nl;
        uint2 st; st.x = 0u; st.y = 0u;
        if (node < N) {
            float acc[4] = {0.f, 0.f, 0.f, 0.f};
            gather16(acc, hs, rps, srcs, node, N, g, t);
            float4 sf = h4_to_f4(*(const uint2*)(hs + (size_t)node * D + t * 4));
            float dv = dinv[node];
            float o0 = fmaxf((acc[0] + sf.x) * dv + b4.x, 0.f);
            float o1 = fmaxf((acc[1] + sf.y) * dv + b4.y, 0.f);
            float o2 = fmaxf((acc[2] + sf.z) * dv + b4.z, 0.f);
            float o3 = fmaxf((acc[3] + sf.w) * dv + b4.w, 0.f);
            __half2 p0 = __floats2half2_rn(o0, o1);
            __half2 p1 = __floats2half2_rn(o2, o3);
            st.x = *(unsigned*)&p0; st.y = *(unsigned*)&p1;
        }
        *(uint2*)(Xh + nl * 72 + t * 4) = st;
    }
    // no __syncthreads(): wave reads only its own Xh rows (lgkmcnt ordering within wave)
    gemm_compute(Xh, Wt, n0, N, dinv, hs2, tid);
}

// ---------------- fused layer-2 aggregation + prediction (2 pairs/wave, no atomics) --------

__global__ __launch_bounds__(256) void k_pred(const __half* __restrict__ hs2, const float* __restrict__ dinv,
                                              const int2* __restrict__ rps, const int* __restrict__ srcs,
                                              const float* __restrict__ b2, const float* __restrict__ pw,
                                              const float* __restrict__ pb,
                                              const int* __restrict__ uidx, const int* __restrict__ jidx,
                                              int U, int N, int B, float* __restrict__ out) {
    int tid = threadIdx.x;
    int lane = tid & 63;
    int g = lane >> 4, t = lane & 15;
    int pair = blockIdx.x * 8 + (tid >> 6) * 2 + (g >> 1);
    if (pair >= B) return;
    int side = g & 1;
    int c = side ? (U + jidx[pair]) : uidx[pair];
    float acc[4] = {0.f, 0.f, 0.f, 0.f};
    gather16(acc, hs2, rps, srcs, c, N, g, t);
    float4 sf = h4_to_f4(*(const uint2*)(hs2 + (size_t)c * D + t * 4));
    float4 b4 = *(const float4*)(b2 + t * 4);
    float dv = dinv[c];
    float4 w4 = *(const float4*)(pw + side * 64 + t * 4);
    float vx = ((acc[0] + sf.x) * dv + b4.x) * w4.x
             + ((acc[1] + sf.y) * dv + b4.y) * w4.y
             + ((acc[2] + sf.z) * dv + b4.z) * w4.z
             + ((acc[3] + sf.w) * dv + b4.w) * w4.w;
    vx += __shfl_xor(vx, 1, 64); vx += __shfl_xor(vx, 2, 64);
    vx += __shfl_xor(vx, 4, 64); vx += __shfl_xor(vx, 8, 64);
    vx += __shfl_xor(vx, 16, 64);   // combine user+job groups of this pair
    if ((lane & 31) == 0) out[pair] = vx + pb[0];
}

// ---------------- host ----------------

extern "C" void kernel_launch(void* const* d_in, const int* in_sizes, int n_in,
                              void* d_out, int out_size, void* d_ws, size_t ws_size,
                              hipStream_t stream) {
    const int*   edge = (const int*)d_in[0];
    const int*   uidx = (const int*)d_in[1];
    const int*   jidx = (const int*)d_in[2];
    const float* xu   = (const float*)d_in[3];
    const float* xj   = (const float*)d_in[4];
    const float* W1   = (const float*)d_in[5];
    const float* b1   = (const float*)d_in[6];
    const float* W2   = (const float*)d_in[7];
    const float* b2   = (const float*)d_in[8];
    const float* pw   = (const float*)d_in[9];
    const float* pb   = (const float*)d_in[10];
    float* out = (float*)d_out;

    int E = in_sizes[0] / 2;
    int B = in_sizes[1];
    int U = in_sizes[3] / D;
    int J = in_sizes[4] / D;
    int N = U + J;
    int nbuk = (N + (1 << BSHIFT) - 1) >> BSHIFT;   // 196 for N=200000; must be <= 256
    const int* row = edge;       // sources
    const int* col = edge + E;   // targets

    char* p = (char*)d_ws;
    auto alloc = [&](size_t bytes) -> void* {
        void* q = (void*)p;
        p += (bytes + 255) / 256 * 256;
        return q;
    };
    size_t capsz = (size_t)nbuk * CAP * 4;               // 16.06 MB
    size_t hs2sz = (size_t)(N + 1) * D * 2;              // 25.6 MB (+ sentinel row)
    int*    bbase   = (int*)alloc(256 * 4);
    int2*   rps     = (int2*)alloc((size_t)N * 8);
    float*  dinv    = (float*)alloc((size_t)N * 4);
    int*    srcs    = (int*)alloc(capsz);
    __half* h       = (__half*)alloc((size_t)(N + 1) * D * 2);  // layer-1 hs (+ sentinel)
    __half* hs2     = (__half*)alloc(hs2sz > capsz ? hs2sz : capsz);
    unsigned* ebuf  = (unsigned*)hs2;                     // ebuf aliases hs2 (dead until agg_gemm2)

    hipMemsetAsync(bbase, 0, 256 * 4, stream);

    // CSR build: staged bucketed binning into fixed-CAP regions, then per-bucket count+scan
    k_bin<<<(E + T_TILE - 1) / T_TILE, 256, 0, stream>>>(row, col, E, bbase, ebuf, nbuk);
    k_csr2a<<<nbuk, 256, 0, stream>>>(ebuf, bbase, N, rps, dinv, h, hs2);

    // fused: srcs scatter (196 blocks) + layer-1 gemm (3125 blocks) — independent work overlapped
    k_csr2b_gemm1<<<nbuk + (N + 63) / 64, 256, 0, stream>>>(ebuf, rps, bbase, N, nbuk, srcs,
                                                            xu, xj, U, W1, dinv, h);

    // fused: layer-1 aggregation (relu, -> wave-private LDS A-rows) + layer-2 gemm -> hs2
    k_agg_gemm2<<<(N + 63) / 64, 256, 0, stream>>>(h, dinv, rps, srcs, b1, W2, N, hs2);

    // layer-2 selected-node aggregation fused with predictor
    k_pred<<<(B + 7) / 8, 256, 0, stream>>>(hs2, dinv, rps, srcs, b2, pw, pb, uidx, jidx, U, N, B, out);
}